// Round 1
// baseline (273.816 us; speedup 1.0000x reference)
//
#include <hip/hip_runtime.h>
#include <math.h>

#define N_ENTC 30000
#define ALL_RELC 221
#define NDIM 32
#define NL 2
#define EVAL_RELC 86
#define BB 16
#define NE 120000
#define ROW (BB * NDIM) /* 512 floats per entity row */

// ---------------------------------------------------------------------------
// Setup: head/tail embeds, relation-attention weights relw[l][b][r], dense flag
// ---------------------------------------------------------------------------
__global__ void k_setup(const int* head, const int* tail, const float* ent_emb,
                        const float* Wrel, const float* brel, const float* Watt,
                        const float* batt, const float* blin,
                        float* relw, float* hemb, float* temb, int* flags)
{
    __shared__ float ht[BB * 2 * NDIM]; // 16 x 64
    __shared__ float h5[BB * 5];
    int tid = threadIdx.x;
    if (tid == 0) {
        int f = 0;
        for (int i = 0; i < NL * NDIM; i++)
            if (blin[i] != 0.0f) f = 1;
        flags[0] = f; // dense fallback if blin != 0 (sparsity proof breaks)
    }
    for (int t = tid; t < BB * NDIM; t += blockDim.x) {
        int b = t >> 5, k = t & 31;
        float hv = ent_emb[(size_t)head[b] * NDIM + k];
        float tv = ent_emb[(size_t)tail[b] * NDIM + k];
        ht[b * 64 + k] = hv;
        ht[b * 64 + 32 + k] = tv;
        hemb[t] = hv;
        temb[t] = tv;
    }
    __syncthreads();
    for (int l = 0; l < NL; l++) {
        for (int t = tid; t < BB * 5; t += blockDim.x) {
            int b = t / 5, j = t % 5;
            float s = brel[l * 5 + j];
            for (int k = 0; k < 2 * NDIM; k++)
                s += ht[b * 64 + k] * Wrel[l * 2 * NDIM * 5 + k * 5 + j];
            h5[t] = s > 0.f ? s : 0.f;
        }
        __syncthreads();
        for (int t = tid; t < BB * ALL_RELC; t += blockDim.x) {
            int b = t / ALL_RELC, r = t % ALL_RELC;
            float s = batt[l * ALL_RELC + r];
            for (int j = 0; j < 5; j++)
                s += h5[b * 5 + j] * Watt[l * 5 * ALL_RELC + j * ALL_RELC + r];
            relw[l * BB * ALL_RELC + t] = 1.0f / (1.0f + expf(-s));
        }
        __syncthreads();
    }
}

// ---------------------------------------------------------------------------
// Clear all three mask buffers (to dense flag); in dense mode also zero hidA
// ---------------------------------------------------------------------------
__global__ void k_clear(unsigned* m0, unsigned* m1, unsigned* m2, float* hidA,
                        const int* flags)
{
    int dense = flags[0];
    unsigned v = dense ? 1u : 0u;
    long stride = (long)gridDim.x * blockDim.x;
    long i0 = (long)blockIdx.x * blockDim.x + threadIdx.x;
    for (long i = i0; i < N_ENTC; i += stride) { m0[i] = v; m1[i] = v; m2[i] = v; }
    if (dense) {
        float4 z = make_float4(0.f, 0.f, 0.f, 0.f);
        float4* p = (float4*)hidA;
        long n4 = (long)N_ENTC * ROW / 4;
        for (long i = i0; i < n4; i += stride) p[i] = z;
    }
}

// ---------------------------------------------------------------------------
// Init: zero the B init rows, place init embeddings, mark mask bits
// ---------------------------------------------------------------------------
__global__ void k_init(float* hidA, unsigned* m0, const float* ent_emb,
                       const int* idx)
{
    int tid = threadIdx.x;
    for (int j = tid; j < BB * ROW; j += blockDim.x) {
        int b = j >> 9;
        hidA[(size_t)idx[b] * ROW + (j & (ROW - 1))] = 0.f;
    }
    __syncthreads();
    if (tid < BB * NDIM) {
        int b = tid >> 5, k = tid & 31;
        hidA[(size_t)idx[b] * ROW + b * NDIM + k] =
            ent_emb[(size_t)idx[b] * NDIM + k];
    }
    if (tid < BB) m0[idx[tid]] = 1u;
}

// ---------------------------------------------------------------------------
// Propagate activity mask one hop along edges
// ---------------------------------------------------------------------------
__global__ void k_maskprop(const unsigned* min_, unsigned* mout,
                           const int* eh, const int* et)
{
    int stride = gridDim.x * blockDim.x;
    for (int e = blockIdx.x * blockDim.x + threadIdx.x; e < NE; e += stride)
        if (min_[eh[e]]) atomicOr(&mout[et[e]], 1u);
}

// ---------------------------------------------------------------------------
// Zero hid rows of active entities (wave per entity)
// ---------------------------------------------------------------------------
__global__ void k_zero_rows(const unsigned* mask, float* hid)
{
    int wid = (blockIdx.x * blockDim.x + threadIdx.x) >> 6;
    int lane = threadIdx.x & 63;
    int nw = (gridDim.x * blockDim.x) >> 6;
    float4 z = make_float4(0.f, 0.f, 0.f, 0.f);
    for (int ent = wid; ent < N_ENTC; ent += nw) {
        if (!mask[ent]) continue;
        float4* p = (float4*)(hid + (size_t)ent * ROW);
        p[lane] = z;
        p[lane + 64] = z;
    }
}

// ---------------------------------------------------------------------------
// Message pass: hidB[et] += hidA[eh] * relw[b][er] * rel_emb[er] * w
// (wave per edge; skips edges whose source row is inactive)
// ---------------------------------------------------------------------------
__global__ void k_msg(const unsigned* min_, const float* hidA, float* hidB,
                      const int* eh, const int* et, const int* er,
                      const float* ew, const float* relw_l, const float* rel_l)
{
    int wid = (blockIdx.x * blockDim.x + threadIdx.x) >> 6;
    int lane = threadIdx.x & 63;
    int nw = (gridDim.x * blockDim.x) >> 6;
    const float4* rv = (const float4*)rel_l;
    for (int e = wid; e < NE; e += nw) {
        if (!min_[eh[e]]) continue;
        int r = er[e];
        float wgt = ew[e];
        const float4* src = (const float4*)(hidA + (size_t)eh[e] * ROW);
        float* dst = hidB + (size_t)et[e] * ROW;
#pragma unroll
        for (int ii = 0; ii < 2; ii++) {
            int i4 = lane + 64 * ii;     // float4 index in row, 0..127
            int b = i4 >> 3;             // sample
            int kq = i4 & 7;             // float4 within dim
            float c = relw_l[b * ALL_RELC + r] * wgt;
            float4 s = src[i4];
            float4 rr = rv[r * 8 + kq];
            atomicAdd(dst + i4 * 4 + 0, s.x * c * rr.x);
            atomicAdd(dst + i4 * 4 + 1, s.y * c * rr.y);
            atomicAdd(dst + i4 * 4 + 2, s.z * c * rr.z);
            atomicAdd(dst + i4 * 4 + 3, s.w * c * rr.w);
        }
    }
}

// ---------------------------------------------------------------------------
// Per-entity linear: hidA[ent] = relu(hidB[ent] @ W + b) (wave per entity)
// ---------------------------------------------------------------------------
__global__ void k_linear(const unsigned* mask, const float* hidB, float* hidA,
                         const float* Wl, const float* bl)
{
    __shared__ float sW[NDIM * NDIM];
    __shared__ float sb[NDIM];
    int tid = threadIdx.x;
    for (int i = tid; i < NDIM * NDIM; i += blockDim.x) sW[i] = Wl[i];
    if (tid < NDIM) sb[tid] = bl[tid];
    __syncthreads();
    int wid = (blockIdx.x * blockDim.x + tid) >> 6;
    int lane = tid & 63;
    int nw = (gridDim.x * blockDim.x) >> 6;
    int b = lane >> 2;            // 4 lanes per sample
    int j0 = (lane & 3) * 8;      // 8 output dims per lane
    for (int ent = wid; ent < N_ENTC; ent += nw) {
        if (!mask[ent]) continue;
        const float4* src = (const float4*)(hidB + (size_t)ent * ROW + b * NDIM);
        float h[NDIM];
#pragma unroll
        for (int q = 0; q < 8; q++) {
            float4 v = src[q];
            h[q * 4 + 0] = v.x; h[q * 4 + 1] = v.y;
            h[q * 4 + 2] = v.z; h[q * 4 + 3] = v.w;
        }
        float acc[8];
#pragma unroll
        for (int jj = 0; jj < 8; jj++) acc[jj] = sb[j0 + jj];
#pragma unroll
        for (int k = 0; k < NDIM; k++) {
            float4 w0 = *(const float4*)&sW[k * NDIM + j0];
            float4 w1 = *(const float4*)&sW[k * NDIM + j0 + 4];
            float hk = h[k];
            acc[0] += hk * w0.x; acc[1] += hk * w0.y;
            acc[2] += hk * w0.z; acc[3] += hk * w0.w;
            acc[4] += hk * w1.x; acc[5] += hk * w1.y;
            acc[6] += hk * w1.z; acc[7] += hk * w1.w;
        }
        float* dst = hidA + (size_t)ent * ROW + b * NDIM + j0;
        float4 o0, o1;
        o0.x = fmaxf(acc[0], 0.f); o0.y = fmaxf(acc[1], 0.f);
        o0.z = fmaxf(acc[2], 0.f); o0.w = fmaxf(acc[3], 0.f);
        o1.x = fmaxf(acc[4], 0.f); o1.y = fmaxf(acc[5], 0.f);
        o1.z = fmaxf(acc[6], 0.f); o1.w = fmaxf(acc[7], 0.f);
        *(float4*)dst = o0;
        *(float4*)(dst + 4) = o1;
    }
}

// ---------------------------------------------------------------------------
// Masked gather of the per-sample result row
// ---------------------------------------------------------------------------
__global__ void k_gather(const float* hidA, const unsigned* mfin, const int* q,
                         float* dst)
{
    int t = threadIdx.x;
    if (t < BB * NDIM) {
        int b = t >> 5;
        int ent = q[b];
        dst[t] = mfin[ent] ? hidA[(size_t)ent * ROW + t] : 0.f;
    }
}

// ---------------------------------------------------------------------------
// Final: out = [hemb|temb|hhid|thid] @ Wr + br   (16 x 86)
// ---------------------------------------------------------------------------
__global__ void k_out(const float* hemb, const float* temb, const float* hhid,
                      const float* thid, const float* Wr, const float* br,
                      float* out)
{
    for (int o = threadIdx.x; o < BB * EVAL_RELC; o += blockDim.x) {
        int b = o / EVAL_RELC, r = o % EVAL_RELC;
        float s = br[r];
        for (int k = 0; k < NDIM; k++) {
            s += hemb[b * NDIM + k] * Wr[(k)*EVAL_RELC + r];
            s += temb[b * NDIM + k] * Wr[(32 + k) * EVAL_RELC + r];
            s += hhid[b * NDIM + k] * Wr[(64 + k) * EVAL_RELC + r];
            s += thid[b * NDIM + k] * Wr[(96 + k) * EVAL_RELC + r];
        }
        out[o] = s;
    }
}

extern "C" void kernel_launch(void* const* d_in, const int* in_sizes, int n_in,
                              void* d_out, int out_size, void* d_ws,
                              size_t ws_size, hipStream_t stream)
{
    const int* head = (const int*)d_in[0];
    const int* tail = (const int*)d_in[1];
    const int* eh = (const int*)d_in[2];
    const int* et = (const int*)d_in[3];
    const int* er = (const int*)d_in[4];
    const float* ew = (const float*)d_in[5];
    const float* ent_emb = (const float*)d_in[6];
    const float* rel_embs = (const float*)d_in[7]; // (2,221,32)
    const float* Wlin = (const float*)d_in[8];     // (2,32,32)
    const float* blin = (const float*)d_in[9];     // (2,32)
    const float* Wrel = (const float*)d_in[10];    // (2,64,5)
    const float* brel = (const float*)d_in[11];    // (2,5)
    const float* Watt = (const float*)d_in[12];    // (2,5,221)
    const float* batt = (const float*)d_in[13];    // (2,221)
    const float* Wr = (const float*)d_in[14];      // (128,86)
    const float* br = (const float*)d_in[15];      // (86,)
    float* out = (float*)d_out;

    // workspace carve (~123.3 MB)
    float* hidA = (float*)d_ws;
    float* hidB = hidA + (size_t)N_ENTC * ROW;
    unsigned* m0 = (unsigned*)(hidB + (size_t)N_ENTC * ROW);
    unsigned* m1 = m0 + N_ENTC;
    unsigned* m2 = m1 + N_ENTC;
    float* relw = (float*)(m2 + N_ENTC);
    float* hemb = relw + (size_t)NL * BB * ALL_RELC;
    float* temb = hemb + BB * NDIM;
    float* hhid = temb + BB * NDIM;
    float* thid = hhid + BB * NDIM;
    int* flags = (int*)(thid + BB * NDIM);

    k_setup<<<1, 256, 0, stream>>>(head, tail, ent_emb, Wrel, brel, Watt, batt,
                                   blin, relw, hemb, temb, flags);

    unsigned* masks[3] = {m0, m1, m2};
    for (int dir = 0; dir < 2; dir++) {
        const int* init_idx = (dir == 0) ? head : tail;
        const int* qidx = (dir == 0) ? tail : head;
        float* dvec = (dir == 0) ? thid : hhid;

        k_clear<<<2048, 256, 0, stream>>>(m0, m1, m2, hidA, flags);
        k_init<<<1, 512, 0, stream>>>(hidA, m0, ent_emb, init_idx);
        for (int l = 0; l < NL; l++) {
            const unsigned* min_ = masks[l];
            unsigned* mout = masks[l + 1];
            k_maskprop<<<512, 256, 0, stream>>>(min_, mout, eh, et);
            k_zero_rows<<<512, 256, 0, stream>>>(mout, hidB);
            k_msg<<<512, 256, 0, stream>>>(
                min_, hidA, hidB, eh, et, er, ew,
                relw + (size_t)l * BB * ALL_RELC,
                rel_embs + (size_t)l * ALL_RELC * NDIM);
            k_linear<<<256, 256, 0, stream>>>(mout, hidB, hidA,
                                              Wlin + (size_t)l * NDIM * NDIM,
                                              blin + (size_t)l * NDIM);
        }
        k_gather<<<1, 512, 0, stream>>>(hidA, m2, qidx, dvec);
    }
    k_out<<<1, 256, 0, stream>>>(hemb, temb, hhid, thid, Wr, br, out);
}

// Round 3
// 262.311 us; speedup vs baseline: 1.0439x; 1.0439x over previous
//
#include <hip/hip_runtime.h>
#include <math.h>

#define N_ENTC 30000
#define ALL_RELC 221
#define NDIM 32
#define NL 2
#define EVAL_RELC 86
#define BB 16
#define NE 120000
#define ROW (BB * NDIM) /* 512 floats per entity row */
#define GRIDX 128
#define BLOCK 256

// Software grid barrier: one single-use counter per phase boundary.
// Counters live in d_ws and are zeroed by k_bar_init before the fused kernel.
__device__ inline void gbar(unsigned* ctr, unsigned nblk)
{
    __syncthreads();
    if (threadIdx.x == 0) {
        __threadfence(); // release all prior writes (device scope)
        __hip_atomic_fetch_add(ctr, 1u, __ATOMIC_ACQ_REL,
                               __HIP_MEMORY_SCOPE_AGENT);
        while (__hip_atomic_load(ctr, __ATOMIC_ACQUIRE,
                                 __HIP_MEMORY_SCOPE_AGENT) < nblk)
            __builtin_amdgcn_s_sleep(2);
        __threadfence();
    }
    __syncthreads();
}

__global__ void k_bar_init(unsigned* p) // zero cnts[8] + bar[8]
{
    if (threadIdx.x < 16) p[threadIdx.x] = 0u;
}

// Single fused kernel. Phases separated by gbar():
//  P0: clear masks (dense: prefill lists + zero hid), block0: relw
//  P1: layer-1 maskprop scan (src = 16 ids in regs, first-touch zero hidB row,
//      collect entity+edge lists); block0: init rows of hidA
//  P2: layer-1 message pass over collected edge list (atomics into hidB)
//  P3: layer-1 linear in-place on hidB  ||  layer-2 maskprop scan
//      (first-touch zero hidA rows)   [disjoint buffers -> same phase]
//  P4: layer-2 message pass (hidB -> hidA)
//  P5: layer-2 linear in-place on hidA
//  P6: block0: gather + final (16x128)@(128x86) output GEMM
__global__ __launch_bounds__(BLOCK) void emer_fused(
    const int* __restrict__ head, const int* __restrict__ tail,
    const int* __restrict__ eh, const int* __restrict__ et,
    const int* __restrict__ er, const float* __restrict__ ew,
    const float* __restrict__ ent_emb, const float* __restrict__ rel_embs,
    const float* __restrict__ Wlin, const float* __restrict__ blin,
    const float* __restrict__ Wrel, const float* __restrict__ brel,
    const float* __restrict__ Watt, const float* __restrict__ batt,
    const float* __restrict__ Wr, const float* __restrict__ br,
    float* __restrict__ out, float* __restrict__ ws)
{
    __shared__ float sW[NL * NDIM * NDIM];
    __shared__ float sb[NL * NDIM];
    __shared__ int s_src[2 * BB]; // [0..15]=head, [16..31]=tail
    __shared__ int s_dense;
    __shared__ float s_ht[BB * 64];
    __shared__ float s_h5[BB * 5];
    __shared__ float sg[4 * BB * NDIM]; // gather: hemb|temb|hhid|thid

    const int tid = blockIdx.x * blockDim.x + threadIdx.x;
    const int nthr = gridDim.x * blockDim.x;
    const int wid = tid >> 6;
    const int nw = nthr >> 6;
    const int lane = threadIdx.x & 63;

    // ---- workspace carve ----
    float* hidA = ws;                                    // [2][N][ROW]
    float* hidB = hidA + (size_t)2 * N_ENTC * ROW;       // [2][N][ROW]
    unsigned* m1 = (unsigned*)(hidB + (size_t)2 * N_ENTC * ROW); // [2][N]
    unsigned* m2 = m1 + 2 * N_ENTC;                      // [2][N]
    int* list1 = (int*)(m2 + 2 * N_ENTC);                // [2][N]
    int* list2 = list1 + 2 * N_ENTC;                     // [2][N]
    int* elist1 = list2 + 2 * N_ENTC;                    // [2][NE]
    int* elist2 = elist1 + 2 * NE;                       // [2][NE]
    int* cnts = elist2 + 2 * NE; // [0-1]cnt1 [2-3]cnt2 [4-5]ecnt1 [6-7]ecnt2
    unsigned* bar = (unsigned*)(cnts + 8);               // [8] barrier ctrs
    float* relw = (float*)(bar + 8);                     // [NL][BB][ALL_REL]

    // =================== P0 ===================
    if (threadIdx.x < BB) {
        s_src[threadIdx.x] = head[threadIdx.x];
        s_src[BB + threadIdx.x] = tail[threadIdx.x];
    }
    for (int i = threadIdx.x; i < NL * NDIM * NDIM; i += blockDim.x)
        sW[i] = Wlin[i];
    if (threadIdx.x < NL * NDIM) sb[threadIdx.x] = blin[threadIdx.x];
    if (threadIdx.x == 0) {
        int f = 0;
        for (int i = 0; i < NL * NDIM; i++) f |= (blin[i] != 0.0f);
        s_dense = f;
    }
    __syncthreads();
    const int dense = s_dense;

    if (!dense) {
        for (int i = tid; i < 2 * N_ENTC; i += nthr) { m1[i] = 0u; m2[i] = 0u; }
    } else {
        for (int i = tid; i < 2 * N_ENTC; i += nthr) { m1[i] = 1u; m2[i] = 1u; }
        for (int i = tid; i < N_ENTC; i += nthr) {
            list1[i] = i; list1[N_ENTC + i] = i;
            list2[i] = i; list2[N_ENTC + i] = i;
        }
        for (int i = tid; i < NE; i += nthr) {
            elist1[i] = i; elist1[NE + i] = i;
            elist2[i] = i; elist2[NE + i] = i;
        }
        if (tid < 4) cnts[tid] = N_ENTC;
        else if (tid < 8) cnts[tid] = NE;
        float4 z = make_float4(0.f, 0.f, 0.f, 0.f);
        float4* p = (float4*)hidA; // hidA+hidB contiguous
        long n4 = (long)4 * N_ENTC * (ROW / 4);
        for (long i = tid; i < n4; i += nthr) p[i] = z;
    }

    if (blockIdx.x == 0) { // relation-attention weights (dir-independent)
        for (int t = threadIdx.x; t < BB * NDIM; t += blockDim.x) {
            int b = t >> 5, k = t & 31;
            s_ht[b * 64 + k] = ent_emb[(size_t)s_src[b] * NDIM + k];
            s_ht[b * 64 + 32 + k] = ent_emb[(size_t)s_src[BB + b] * NDIM + k];
        }
        __syncthreads();
        for (int l = 0; l < NL; l++) {
            for (int t = threadIdx.x; t < BB * 5; t += blockDim.x) {
                int b = t / 5, j = t % 5;
                float s = brel[l * 5 + j];
                for (int k = 0; k < 64; k++)
                    s += s_ht[b * 64 + k] * Wrel[l * 64 * 5 + k * 5 + j];
                s_h5[t] = fmaxf(s, 0.f);
            }
            __syncthreads();
            for (int t = threadIdx.x; t < BB * ALL_RELC; t += blockDim.x) {
                int b = t / ALL_RELC, r = t % ALL_RELC;
                float s = batt[l * ALL_RELC + r];
                for (int j = 0; j < 5; j++)
                    s += s_h5[b * 5 + j] * Watt[l * 5 * ALL_RELC + j * ALL_RELC + r];
                relw[l * BB * ALL_RELC + t] = 1.0f / (1.0f + expf(-s));
            }
            __syncthreads();
        }
    }
    gbar(&bar[0], GRIDX); // ---- S1 ----

    // =================== P1: layer-1 maskprop ===================
    if (!dense) {
        for (int d = 0; d < 2; d++) {
            int sv[BB];
#pragma unroll
            for (int i = 0; i < BB; i++) sv[i] = s_src[d * BB + i];
            unsigned* m1d = m1 + d * N_ENTC;
            int* l1d = list1 + d * N_ENTC;
            int* e1d = elist1 + d * NE;
            float* hB = hidB + (size_t)d * N_ENTC * ROW;
            for (int e = tid; e < NE; e += nthr) {
                int u = eh[e];
                bool act = false;
#pragma unroll
                for (int i = 0; i < BB; i++) act |= (u == sv[i]);
                if (!act) continue;
                int ep = atomicAdd(&cnts[4 + d], 1);
                e1d[ep] = e;
                int t_ = et[e];
                if (atomicOr(&m1d[t_], 1u) == 0u) {
                    int lp = atomicAdd(&cnts[0 + d], 1);
                    l1d[lp] = t_;
                    float4 z = make_float4(0.f, 0.f, 0.f, 0.f);
                    float4* pz = (float4*)(hB + (size_t)t_ * ROW);
                    for (int q = 0; q < ROW / 4; q++) pz[q] = z;
                }
            }
        }
    }
    if (blockIdx.x == 0) { // init rows of hidA (both dirs)
        for (int j = threadIdx.x; j < 2 * BB * ROW; j += blockDim.x) {
            int d = j >> 13; // / (BB*ROW)
            int jj = j & (BB * ROW - 1);
            int b = jj >> 9;
            int ent = s_src[d * BB + b];
            hidA[(size_t)d * N_ENTC * ROW + (size_t)ent * ROW + (jj & (ROW - 1))] = 0.f;
        }
        __syncthreads();
        for (int t = threadIdx.x; t < 2 * BB * NDIM; t += blockDim.x) {
            int d = t >> 9;
            int tt = t & (BB * NDIM - 1);
            int b = tt >> 5, k = tt & 31;
            int ent = s_src[d * BB + b];
            hidA[(size_t)d * N_ENTC * ROW + (size_t)ent * ROW + b * NDIM + k] =
                ent_emb[(size_t)ent * NDIM + k];
        }
    }
    gbar(&bar[1], GRIDX); // ---- S2 ----

    // =================== P2: layer-1 messages ===================
    for (int d = 0; d < 2; d++) {
        int ec = cnts[4 + d];
        const int* e1d = elist1 + d * NE;
        const float* hA = hidA + (size_t)d * N_ENTC * ROW;
        float* hB = hidB + (size_t)d * N_ENTC * ROW;
        const float* rw = relw; // layer 0
        const float4* rv = (const float4*)rel_embs;
        for (int j = wid; j < ec; j += nw) {
            int e = e1d[j];
            int u = eh[e], t_ = et[e], r = er[e];
            float wgt = ew[e];
            const float4* src = (const float4*)(hA + (size_t)u * ROW);
            float* dst = hB + (size_t)t_ * ROW;
#pragma unroll
            for (int ii = 0; ii < 2; ii++) {
                int i4 = lane + 64 * ii;
                int b = i4 >> 3, kq = i4 & 7;
                float c = rw[b * ALL_RELC + r] * wgt;
                float4 s = src[i4];
                float4 rr = rv[r * 8 + kq];
                atomicAdd(dst + i4 * 4 + 0, s.x * c * rr.x);
                atomicAdd(dst + i4 * 4 + 1, s.y * c * rr.y);
                atomicAdd(dst + i4 * 4 + 2, s.z * c * rr.z);
                atomicAdd(dst + i4 * 4 + 3, s.w * c * rr.w);
            }
        }
    }
    gbar(&bar[2], GRIDX); // ---- S3 ----

    // =================== P3: layer-1 linear (in-place, hidB) + layer-2 maskprop ===================
    {
        const float* sWl = sW;
        const float* sbl = sb;
        int b = lane >> 2;
        int j0 = (lane & 3) * 8;
        for (int d = 0; d < 2; d++) {
            int nc = cnts[0 + d];
            const int* l1d = list1 + d * N_ENTC;
            float* hB = hidB + (size_t)d * N_ENTC * ROW;
            for (int j = wid; j < nc; j += nw) {
                float* rowp = hB + (size_t)l1d[j] * ROW + b * NDIM;
                const float4* src = (const float4*)rowp;
                float h[NDIM];
#pragma unroll
                for (int q = 0; q < 8; q++) {
                    float4 v = src[q];
                    h[q * 4 + 0] = v.x; h[q * 4 + 1] = v.y;
                    h[q * 4 + 2] = v.z; h[q * 4 + 3] = v.w;
                }
                float acc[8];
#pragma unroll
                for (int jj = 0; jj < 8; jj++) acc[jj] = sbl[j0 + jj];
#pragma unroll
                for (int k = 0; k < NDIM; k++) {
                    float4 w0 = *(const float4*)&sWl[k * NDIM + j0];
                    float4 w1 = *(const float4*)&sWl[k * NDIM + j0 + 4];
                    float hk = h[k];
                    acc[0] += hk * w0.x; acc[1] += hk * w0.y;
                    acc[2] += hk * w0.z; acc[3] += hk * w0.w;
                    acc[4] += hk * w1.x; acc[5] += hk * w1.y;
                    acc[6] += hk * w1.z; acc[7] += hk * w1.w;
                }
                float4 o0, o1;
                o0.x = fmaxf(acc[0], 0.f); o0.y = fmaxf(acc[1], 0.f);
                o0.z = fmaxf(acc[2], 0.f); o0.w = fmaxf(acc[3], 0.f);
                o1.x = fmaxf(acc[4], 0.f); o1.y = fmaxf(acc[5], 0.f);
                o1.z = fmaxf(acc[6], 0.f); o1.w = fmaxf(acc[7], 0.f);
                *(float4*)(rowp + j0) = o0;
                *(float4*)(rowp + j0 + 4) = o1;
            }
        }
    }
    if (!dense) {
        for (int d = 0; d < 2; d++) {
            const unsigned* m1d = m1 + d * N_ENTC;
            unsigned* m2d = m2 + d * N_ENTC;
            int* l2d = list2 + d * N_ENTC;
            int* e2d = elist2 + d * NE;
            float* hA = hidA + (size_t)d * N_ENTC * ROW;
            for (int e = tid; e < NE; e += nthr) {
                if (!m1d[eh[e]]) continue;
                int ep = atomicAdd(&cnts[6 + d], 1);
                e2d[ep] = e;
                int t_ = et[e];
                if (atomicOr(&m2d[t_], 1u) == 0u) {
                    int lp = atomicAdd(&cnts[2 + d], 1);
                    l2d[lp] = t_;
                    float4 z = make_float4(0.f, 0.f, 0.f, 0.f);
                    float4* pz = (float4*)(hA + (size_t)t_ * ROW);
                    for (int q = 0; q < ROW / 4; q++) pz[q] = z;
                }
            }
        }
    } else { // dense: hidA must be all-zero before layer-2 messages
        float4 z = make_float4(0.f, 0.f, 0.f, 0.f);
        float4* p = (float4*)hidA;
        long n4 = (long)2 * N_ENTC * (ROW / 4);
        for (long i = tid; i < n4; i += nthr) p[i] = z;
    }
    gbar(&bar[3], GRIDX); // ---- S4 ----

    // =================== P4: layer-2 messages (hidB -> hidA) ===================
    for (int d = 0; d < 2; d++) {
        int ec = cnts[6 + d];
        const int* e2d = elist2 + d * NE;
        const float* hB = hidB + (size_t)d * N_ENTC * ROW;
        float* hA = hidA + (size_t)d * N_ENTC * ROW;
        const float* rw = relw + BB * ALL_RELC; // layer 1
        const float4* rv = (const float4*)(rel_embs + (size_t)ALL_RELC * NDIM);
        for (int j = wid; j < ec; j += nw) {
            int e = e2d[j];
            int u = eh[e], t_ = et[e], r = er[e];
            float wgt = ew[e];
            const float4* src = (const float4*)(hB + (size_t)u * ROW);
            float* dst = hA + (size_t)t_ * ROW;
#pragma unroll
            for (int ii = 0; ii < 2; ii++) {
                int i4 = lane + 64 * ii;
                int b = i4 >> 3, kq = i4 & 7;
                float c = rw[b * ALL_RELC + r] * wgt;
                float4 s = src[i4];
                float4 rr = rv[r * 8 + kq];
                atomicAdd(dst + i4 * 4 + 0, s.x * c * rr.x);
                atomicAdd(dst + i4 * 4 + 1, s.y * c * rr.y);
                atomicAdd(dst + i4 * 4 + 2, s.z * c * rr.z);
                atomicAdd(dst + i4 * 4 + 3, s.w * c * rr.w);
            }
        }
    }
    gbar(&bar[4], GRIDX); // ---- S5 ----

    // =================== P5: layer-2 linear (in-place, hidA) ===================
    {
        const float* sWl = sW + NDIM * NDIM;
        const float* sbl = sb + NDIM;
        int b = lane >> 2;
        int j0 = (lane & 3) * 8;
        for (int d = 0; d < 2; d++) {
            int nc = cnts[2 + d];
            const int* l2d = list2 + d * N_ENTC;
            float* hA = hidA + (size_t)d * N_ENTC * ROW;
            for (int j = wid; j < nc; j += nw) {
                float* rowp = hA + (size_t)l2d[j] * ROW + b * NDIM;
                const float4* src = (const float4*)rowp;
                float h[NDIM];
#pragma unroll
                for (int q = 0; q < 8; q++) {
                    float4 v = src[q];
                    h[q * 4 + 0] = v.x; h[q * 4 + 1] = v.y;
                    h[q * 4 + 2] = v.z; h[q * 4 + 3] = v.w;
                }
                float acc[8];
#pragma unroll
                for (int jj = 0; jj < 8; jj++) acc[jj] = sbl[j0 + jj];
#pragma unroll
                for (int k = 0; k < NDIM; k++) {
                    float4 w0 = *(const float4*)&sWl[k * NDIM + j0];
                    float4 w1 = *(const float4*)&sWl[k * NDIM + j0 + 4];
                    float hk = h[k];
                    acc[0] += hk * w0.x; acc[1] += hk * w0.y;
                    acc[2] += hk * w0.z; acc[3] += hk * w0.w;
                    acc[4] += hk * w1.x; acc[5] += hk * w1.y;
                    acc[6] += hk * w1.z; acc[7] += hk * w1.w;
                }
                float4 o0, o1;
                o0.x = fmaxf(acc[0], 0.f); o0.y = fmaxf(acc[1], 0.f);
                o0.z = fmaxf(acc[2], 0.f); o0.w = fmaxf(acc[3], 0.f);
                o1.x = fmaxf(acc[4], 0.f); o1.y = fmaxf(acc[5], 0.f);
                o1.z = fmaxf(acc[6], 0.f); o1.w = fmaxf(acc[7], 0.f);
                *(float4*)(rowp + j0) = o0;
                *(float4*)(rowp + j0 + 4) = o1;
            }
        }
    }
    gbar(&bar[5], GRIDX); // ---- S6 ----

    // =================== P6: gather + output GEMM (block 0) ===================
    if (blockIdx.x == 0) {
        for (int t = threadIdx.x; t < BB * NDIM; t += blockDim.x) {
            int b = t >> 5, k = t & 31;
            int he = s_src[b], te = s_src[BB + b];
            sg[t] = ent_emb[(size_t)he * NDIM + k];          // hemb
            sg[512 + t] = ent_emb[(size_t)te * NDIM + k];    // temb
            // head_hid: dir1 (init=tail), query=head, mask m2[dir1]
            sg[1024 + t] = m2[N_ENTC + he]
                ? hidA[(size_t)N_ENTC * ROW + (size_t)he * ROW + b * NDIM + k] : 0.f;
            // tail_hid: dir0 (init=head), query=tail, mask m2[dir0]
            sg[1536 + t] = m2[te]
                ? hidA[(size_t)te * ROW + b * NDIM + k] : 0.f;
        }
        __syncthreads();
        for (int o = threadIdx.x; o < BB * EVAL_RELC; o += blockDim.x) {
            int b = o / EVAL_RELC, r = o % EVAL_RELC;
            float s = br[r];
            for (int k = 0; k < 4 * NDIM; k++)
                s += sg[(k >> 5) * 512 + b * NDIM + (k & 31)] * Wr[k * EVAL_RELC + r];
            out[o] = s;
        }
    }
}

extern "C" void kernel_launch(void* const* d_in, const int* in_sizes, int n_in,
                              void* d_out, int out_size, void* d_ws,
                              size_t ws_size, hipStream_t stream)
{
    const int* head = (const int*)d_in[0];
    const int* tail = (const int*)d_in[1];
    const int* eh = (const int*)d_in[2];
    const int* et = (const int*)d_in[3];
    const int* er = (const int*)d_in[4];
    const float* ew = (const float*)d_in[5];
    const float* ent_emb = (const float*)d_in[6];
    const float* rel_embs = (const float*)d_in[7];
    const float* Wlin = (const float*)d_in[8];
    const float* blin = (const float*)d_in[9];
    const float* Wrel = (const float*)d_in[10];
    const float* brel = (const float*)d_in[11];
    const float* Watt = (const float*)d_in[12];
    const float* batt = (const float*)d_in[13];
    const float* Wr = (const float*)d_in[14];
    const float* br = (const float*)d_in[15];
    float* out = (float*)d_out;
    float* ws = (float*)d_ws;

    // cnts+bar live right after the two hid buffers, masks and lists:
    // offset (in 4B words) = 4*N*ROW + 4*N (m1,m2) + 4*N (list1,list2) + 4*NE
    size_t off = (size_t)4 * N_ENTC * ROW + (size_t)8 * N_ENTC + (size_t)4 * NE;
    unsigned* cnts_bar = (unsigned*)ws + off;

    k_bar_init<<<1, 64, 0, stream>>>(cnts_bar);

    emer_fused<<<GRIDX, BLOCK, 0, stream>>>(
        head, tail, eh, et, er, ew, ent_emb, rel_embs, Wlin, blin,
        Wrel, brel, Watt, batt, Wr, br, out, ws);
}

// Round 4
// 202.791 us; speedup vs baseline: 1.3502x; 1.2935x over previous
//
#include <hip/hip_runtime.h>
#include <math.h>

#define N_ENTC 30000
#define ALL_RELC 221
#define NDIM 32
#define EVAL_RELC 86
#define BB 16
#define NE 120000
#define ROW 512           /* BB*NDIM floats per entity row */
#define BLOCK 512
#define MW 938            /* bitmask words for 30000 entities */
#define MAGIC 0x5F3759DFu

// One block per propagation direction (d=0: init=head,query=tail -> tail_hid;
// d=1: init=tail,query=head -> head_hid). All intra-direction ordering is
// __syncthreads (single CU => same L1, no device fences needed). The only
// cross-block sync is a one-way flag before the final output GEMM (block 0).
//
// Exact for ANY input values (incl. blin != 0):
//   - layer-1 messages only come from init rows (hid0 zero elsewhere)
//   - only M = {heads of edges into Q} need layer-1 outputs
//   - only the 16 Q rows need layer-2 outputs (bias included generically)
__global__ __launch_bounds__(BLOCK) void emer_path(
    const int* __restrict__ head, const int* __restrict__ tail,
    const int* __restrict__ eh, const int* __restrict__ et,
    const int* __restrict__ er, const float* __restrict__ ew,
    const float* __restrict__ ent_emb, const float* __restrict__ rel_embs,
    const float* __restrict__ Wlin, const float* __restrict__ blin,
    const float* __restrict__ Wrel, const float* __restrict__ brel,
    const float* __restrict__ Watt, const float* __restrict__ batt,
    const float* __restrict__ Wr, const float* __restrict__ br,
    float* __restrict__ out, float* __restrict__ ws)
{
    __shared__ float s_relw[2 * BB * ALL_RELC]; // 7072 f; reused as sx in final
    __shared__ float s_W[2 * NDIM * NDIM];
    __shared__ float s_b[2 * NDIM];
    __shared__ float s_ht[BB * 64];             // reused to stash thid (block0)
    __shared__ float s_h5[BB * 5];
    __shared__ unsigned s_mS[MW], s_mQ[MW], s_mM[MW];
    __shared__ int s_src[2 * BB];               // [0..16)=head, [16..32)=tail
    __shared__ int s_ec1, s_ec2, s_cm;

    const int t = threadIdx.x;
    const int d = blockIdx.x;
    const int wid = t >> 6, lane = t & 63;

    // ---- workspace carve ----
    float* hidA = ws + (size_t)d * N_ENTC * ROW;
    float* hidB = ws + (size_t)(2 + d) * N_ENTC * ROW;
    int* ibase = (int*)(ws + (size_t)4 * N_ENTC * ROW);
    int* elist1 = ibase + (size_t)d * NE;
    int* elist2 = ibase + 2 * NE + (size_t)d * NE;
    int* Mlist = ibase + 4 * NE + (size_t)d * N_ENTC;
    float* staging = (float*)(ibase + 4 * NE + 2 * N_ENTC); // [2][512]
    unsigned* flag = (unsigned*)(staging + 1024);

    // =================== P0a: loads ===================
    if (t < BB) { s_src[t] = head[t]; s_src[BB + t] = tail[t]; }
    for (int i = t; i < 2 * NDIM * NDIM; i += BLOCK) s_W[i] = Wlin[i];
    if (t < 2 * NDIM) s_b[t] = blin[t];
    for (int i = t; i < MW; i += BLOCK) { s_mS[i] = 0u; s_mQ[i] = 0u; s_mM[i] = 0u; }
    if (t == 0) { s_ec1 = 0; s_ec2 = 0; s_cm = 0; }
    __syncthreads();

    const int* sv = s_src + d * BB;        // init (source) entities
    const int* qv = s_src + (1 - d) * BB;  // query entities

    // =================== P0b: bits, ht, zero init rows ===================
    if (t < BB) {
        int s = sv[t]; atomicOr(&s_mS[s >> 5], 1u << (s & 31));
        int q = qv[t]; atomicOr(&s_mQ[q >> 5], 1u << (q & 31));
    }
    for (int i = t; i < BB * NDIM; i += BLOCK) {
        int b = i >> 5, k = i & 31;
        s_ht[b * 64 + k] = ent_emb[(size_t)s_src[b] * NDIM + k];
        s_ht[b * 64 + 32 + k] = ent_emb[(size_t)s_src[BB + b] * NDIM + k];
    }
    for (int i = t; i < BB * ROW; i += BLOCK) {
        int b = i >> 9;
        hidA[(size_t)sv[b] * ROW + (i & (ROW - 1))] = 0.f;
    }
    __syncthreads();
    // set init segments (after zero: duplicate init ids get all their segments)
    {
        int b = t >> 5, k = t & 31; // BLOCK == BB*NDIM == 512
        hidA[(size_t)sv[b] * ROW + b * NDIM + k] =
            ent_emb[(size_t)sv[b] * NDIM + k];
    }
    // relation-attention weights, both layers
    for (int l = 0; l < 2; l++) {
        for (int i = t; i < BB * 5; i += BLOCK) {
            int b = i / 5, j = i % 5;
            float s = brel[l * 5 + j];
            for (int k = 0; k < 64; k++)
                s += s_ht[b * 64 + k] * Wrel[l * 320 + k * 5 + j];
            s_h5[i] = fmaxf(s, 0.f);
        }
        __syncthreads();
        for (int i = t; i < BB * ALL_RELC; i += BLOCK) {
            int b = i / ALL_RELC, r = i % ALL_RELC;
            float s = batt[l * ALL_RELC + r];
            for (int j = 0; j < 5; j++)
                s += s_h5[b * 5 + j] * Watt[l * 5 * ALL_RELC + j * ALL_RELC + r];
            s_relw[l * BB * ALL_RELC + i] = 1.0f / (1.0f + expf(-s));
        }
        __syncthreads();
    }

    // =================== P1: single edge scan -> elist1 (eh in S), elist2 (et in Q)
    for (int i = t; i < NE / 4; i += BLOCK) {
        int4 h4 = ((const int4*)eh)[i];
        int4 t4 = ((const int4*)et)[i];
        int e0 = 4 * i;
        int hv[4] = {h4.x, h4.y, h4.z, h4.w};
        int tv[4] = {t4.x, t4.y, t4.z, t4.w};
#pragma unroll
        for (int c = 0; c < 4; c++) {
            if ((s_mS[hv[c] >> 5] >> (hv[c] & 31)) & 1u) {
                int p = atomicAdd(&s_ec1, 1);
                elist1[p] = e0 + c;
            }
            if ((s_mQ[tv[c] >> 5] >> (tv[c] & 31)) & 1u) {
                int p = atomicAdd(&s_ec2, 1);
                elist2[p] = e0 + c;
            }
        }
    }
    __syncthreads();
    const int ec1 = s_ec1, ec2 = s_ec2;

    // =================== P2: build M = distinct heads of elist2 ===================
    for (int j = t; j < ec2; j += BLOCK) {
        int h = eh[elist2[j]];
        unsigned bit = 1u << (h & 31);
        unsigned old = atomicOr(&s_mM[h >> 5], bit);
        if (!(old & bit)) { int p = atomicAdd(&s_cm, 1); Mlist[p] = h; }
    }
    __syncthreads();
    const int cm = s_cm;

    // =================== P3: zero hidB rows of M ===================
    {
        float4 z = make_float4(0.f, 0.f, 0.f, 0.f);
        for (int j = wid; j < cm; j += BLOCK / 64) {
            float4* p = (float4*)(hidB + (size_t)Mlist[j] * ROW);
            p[lane] = z; p[lane + 64] = z;
        }
    }
    __syncthreads();

    // =================== P4: layer-1 messages (elist1 filtered to et in M) ====
    {
        const float4* rv = (const float4*)rel_embs;
        for (int j = wid; j < ec1; j += BLOCK / 64) {
            int e = elist1[j];
            int tt = et[e];
            if (!((s_mM[tt >> 5] >> (tt & 31)) & 1u)) continue;
            int r = er[e];
            float wgt = ew[e];
            const float4* src = (const float4*)(hidA + (size_t)eh[e] * ROW);
            float* dst = hidB + (size_t)tt * ROW;
#pragma unroll
            for (int ii = 0; ii < 2; ii++) {
                int i4 = lane + 64 * ii;
                int b = i4 >> 3, kq = i4 & 7;
                float c = s_relw[b * ALL_RELC + r] * wgt;
                float4 s = src[i4];
                float4 rr = rv[r * 8 + kq];
                atomicAdd(dst + i4 * 4 + 0, s.x * c * rr.x);
                atomicAdd(dst + i4 * 4 + 1, s.y * c * rr.y);
                atomicAdd(dst + i4 * 4 + 2, s.z * c * rr.z);
                atomicAdd(dst + i4 * 4 + 3, s.w * c * rr.w);
            }
        }
    }
    __syncthreads();

    // =================== P5: zero hidA Q rows + layer-1 linear (M rows, hidB) =
    for (int i = t; i < BB * ROW; i += BLOCK) {
        int b = i >> 9;
        hidA[(size_t)qv[b] * ROW + (i & (ROW - 1))] = 0.f;
    }
    {
        int b = lane >> 2;
        int j0 = (lane & 3) * 8;
        for (int j = wid; j < cm; j += BLOCK / 64) {
            float* rowp = hidB + (size_t)Mlist[j] * ROW + b * NDIM;
            const float4* src = (const float4*)rowp;
            float h[NDIM];
#pragma unroll
            for (int q = 0; q < 8; q++) {
                float4 v = src[q];
                h[q * 4 + 0] = v.x; h[q * 4 + 1] = v.y;
                h[q * 4 + 2] = v.z; h[q * 4 + 3] = v.w;
            }
            float acc[8];
#pragma unroll
            for (int jj = 0; jj < 8; jj++) acc[jj] = s_b[j0 + jj];
#pragma unroll
            for (int k = 0; k < NDIM; k++) {
                float4 w0 = *(const float4*)&s_W[k * NDIM + j0];
                float4 w1 = *(const float4*)&s_W[k * NDIM + j0 + 4];
                float hk = h[k];
                acc[0] += hk * w0.x; acc[1] += hk * w0.y;
                acc[2] += hk * w0.z; acc[3] += hk * w0.w;
                acc[4] += hk * w1.x; acc[5] += hk * w1.y;
                acc[6] += hk * w1.z; acc[7] += hk * w1.w;
            }
            float4 o0, o1;
            o0.x = fmaxf(acc[0], 0.f); o0.y = fmaxf(acc[1], 0.f);
            o0.z = fmaxf(acc[2], 0.f); o0.w = fmaxf(acc[3], 0.f);
            o1.x = fmaxf(acc[4], 0.f); o1.y = fmaxf(acc[5], 0.f);
            o1.z = fmaxf(acc[6], 0.f); o1.w = fmaxf(acc[7], 0.f);
            *(float4*)(rowp + j0) = o0;
            *(float4*)(rowp + j0 + 4) = o1;
        }
    }
    __syncthreads();

    // =================== P6: layer-2 messages (elist2: hidB[M] -> hidA[Q]) ====
    {
        const float* rw = s_relw + BB * ALL_RELC;
        const float4* rv = (const float4*)(rel_embs + (size_t)ALL_RELC * NDIM);
        for (int j = wid; j < ec2; j += BLOCK / 64) {
            int e = elist2[j];
            int r = er[e];
            float wgt = ew[e];
            const float4* src = (const float4*)(hidB + (size_t)eh[e] * ROW);
            float* dst = hidA + (size_t)et[e] * ROW;
#pragma unroll
            for (int ii = 0; ii < 2; ii++) {
                int i4 = lane + 64 * ii;
                int b = i4 >> 3, kq = i4 & 7;
                float c = rw[b * ALL_RELC + r] * wgt;
                float4 s = src[i4];
                float4 rr = rv[r * 8 + kq];
                atomicAdd(dst + i4 * 4 + 0, s.x * c * rr.x);
                atomicAdd(dst + i4 * 4 + 1, s.y * c * rr.y);
                atomicAdd(dst + i4 * 4 + 2, s.z * c * rr.z);
                atomicAdd(dst + i4 * 4 + 3, s.w * c * rr.w);
            }
        }
    }
    __syncthreads();

    // =================== P7: layer-2 linear, only (q[b], sample b) segments ===
    {
        int b = t >> 5, j = t & 31; // 512 outputs = 16 samples x 32 dims
        const float* hrow = hidA + (size_t)qv[b] * ROW + b * NDIM;
        float s = s_b[NDIM + j];
        for (int k = 0; k < NDIM; k++)
            s += hrow[k] * s_W[NDIM * NDIM + k * NDIM + j];
        float val = fmaxf(s, 0.f);
        staging[d * 512 + t] = val;
        if (d == 0) s_ht[t] = val; // block0 keeps its own result in LDS
    }
    __syncthreads();

    // =================== cross-block handoff + final GEMM ===================
    if (d == 1) {
        if (t == 0) {
            __builtin_amdgcn_fence(__ATOMIC_RELEASE, "agent");
            __hip_atomic_store(flag, MAGIC, __ATOMIC_RELAXED,
                               __HIP_MEMORY_SCOPE_AGENT);
        }
        return;
    }
    if (t == 0) {
        while (__hip_atomic_load(flag, __ATOMIC_RELAXED,
                                 __HIP_MEMORY_SCOPE_AGENT) != MAGIC)
            __builtin_amdgcn_s_sleep(8);
        __builtin_amdgcn_fence(__ATOMIC_ACQUIRE, "agent");
    }
    __syncthreads();

    float* sx = s_relw; // reuse: [16][128] = hemb|temb|head_hid|tail_hid
    {
        int b = t >> 5, k = t & 31;
        sx[b * 128 + k] = ent_emb[(size_t)s_src[b] * NDIM + k];       // hemb
        sx[b * 128 + 32 + k] = ent_emb[(size_t)s_src[BB + b] * NDIM + k]; // temb
        sx[b * 128 + 64 + k] = staging[512 + b * 32 + k]; // head_hid (dir 1)
        sx[b * 128 + 96 + k] = s_ht[b * 32 + k];          // tail_hid (dir 0, LDS)
    }
    __syncthreads();
    for (int o = t; o < BB * EVAL_RELC; o += BLOCK) {
        int b = o / EVAL_RELC, r = o % EVAL_RELC;
        float s = br[r];
        for (int k = 0; k < 128; k++)
            s += sx[b * 128 + k] * Wr[k * EVAL_RELC + r];
        out[o] = s;
    }
}

extern "C" void kernel_launch(void* const* d_in, const int* in_sizes, int n_in,
                              void* d_out, int out_size, void* d_ws,
                              size_t ws_size, hipStream_t stream)
{
    const int* head = (const int*)d_in[0];
    const int* tail = (const int*)d_in[1];
    const int* eh = (const int*)d_in[2];
    const int* et = (const int*)d_in[3];
    const int* er = (const int*)d_in[4];
    const float* ew = (const float*)d_in[5];
    const float* ent_emb = (const float*)d_in[6];
    const float* rel_embs = (const float*)d_in[7];
    const float* Wlin = (const float*)d_in[8];
    const float* blin = (const float*)d_in[9];
    const float* Wrel = (const float*)d_in[10];
    const float* brel = (const float*)d_in[11];
    const float* Watt = (const float*)d_in[12];
    const float* batt = (const float*)d_in[13];
    const float* Wr = (const float*)d_in[14];
    const float* br = (const float*)d_in[15];
    float* out = (float*)d_out;
    float* ws = (float*)d_ws;

    emer_path<<<2, BLOCK, 0, stream>>>(
        head, tail, eh, et, er, ew, ent_emb, rel_embs, Wlin, blin,
        Wrel, brel, Watt, batt, Wr, br, out, ws);
}

// Round 5
// 176.032 us; speedup vs baseline: 1.5555x; 1.1520x over previous
//
#include <hip/hip_runtime.h>
#include <math.h>

#define N_ENTC 30000
#define ALL_RELC 221
#define NDIM 32
#define EVAL_RELC 86
#define BB 16
#define NE 120000
#define ROW 512            /* BB*NDIM floats per entity row */
#define BLOCK 512
#define NSCAN 120          /* scan blocks; NSCAN*EPB == NE */
#define EPB 1000
#define CAPE 2304          /* LDS compact-list capacity per list */
#define MW 938             /* bitmask words for 30000 entities */
#define TAGE 0x40000000u   /* entry-published tag (poison 0xAAAAAAAA bit30=0) */
#define TAGC 0x5A000000u   /* count-published tag (poison top byte 0xAA) */
#define MAGIC 0x5F3759DFu

// Grid = 120 blocks. All blocks: scan a 1000-edge stripe into 4 stripe-local
// lists (L1d0: eh in H, L1d1: eh in T, L2d0: et in T, L2d1: et in H), publish
// counts via tagged relaxed agent atomics (no fences, no init: tags are
// distinguishable from 0xAA poison). Blocks >=2 exit. Blocks 0/1 = one per
// direction: compute relw/weights (overlapped with other blocks' scans), poll
// counts, compact lists (LDS, global fallback), then run the latency-tail:
//   M = distinct heads of L2 (zero+linear rows -> exact for any blin),
//   layer-1 messages sourced from LDS (hid0 rows are ent_emb of init ids),
//   layer-1 linear on M, layer-2 messages into 16-row Qacc, final linear,
//   R4-proven fence+MAGIC handoff, output GEMM on block 0.
__global__ __launch_bounds__(BLOCK) void emer_scan_path(
    const int* __restrict__ head, const int* __restrict__ tail,
    const int* __restrict__ eh, const int* __restrict__ et,
    const int* __restrict__ er, const float* __restrict__ ew,
    const float* __restrict__ ent_emb, const float* __restrict__ rel_embs,
    const float* __restrict__ Wlin, const float* __restrict__ blin,
    const float* __restrict__ Wrel, const float* __restrict__ brel,
    const float* __restrict__ Watt, const float* __restrict__ batt,
    const float* __restrict__ Wr, const float* __restrict__ br,
    float* __restrict__ out, float* __restrict__ ws)
{
    __shared__ float smem[16250]; // 65,000 B, carved below
    float* s_relw = smem;                  // 7072 f (layer0 @0, layer1 @3536)
    float* s_W = smem + 7072;              // 2048 f
    float* s_b = smem + 9120;              // 64 f
    float* s_ht = smem + 9184;             // 1024 f: [b][head 32|tail 32]
    int* s_src = (int*)(smem + 10208);     // 32 ints
    float* s_h5 = smem + 10240;            // 80 f
    int* s_cnt = (int*)(smem + 10320);     // 16 ints
    float* s_scr = smem + 10336;           // 5914 f scratch (overlaid)
    // scan:  mH = scr[0..938), mT = scr[938..1876)
    // tail:  mM = scr[0..938), pf = scr[938..1066), cnts = scr[1066..1306),
    //        cl1 = scr[1306..3610), cl2 = scr[3610..5914)
    unsigned* mH = (unsigned*)s_scr;
    unsigned* mT = (unsigned*)(s_scr + MW);
    unsigned* mM = (unsigned*)s_scr;
    int* s_pf = (int*)(s_scr + MW);
    int* s_cnts = (int*)(s_scr + MW + 128);
    int* s_cl1 = (int*)(s_scr + 1306);
    int* s_cl2 = (int*)(s_scr + 3610);

    const int t = threadIdx.x;
    const int bid = blockIdx.x;
    const int wid8 = t >> 6, lane = t & 63;

    // ---- workspace carve ----
    float* hidB = ws;                                   // [2][N][ROW]
    unsigned* elistS = (unsigned*)(ws + (size_t)2 * N_ENTC * ROW); // [4][NE]
    int* gcomp = (int*)(elistS + (size_t)4 * NE);       // [4][NE] fallback
    int* MlistB = gcomp + (size_t)4 * NE;               // [2][NE]
    float* qaccB = (float*)(MlistB + (size_t)2 * NE);   // [2][16][512]
    float* staging = qaccB + 2 * BB * ROW;              // [2][512]
    unsigned* flags = (unsigned*)(staging + 1024);      // [480]
    unsigned* hflag = flags + 500;

    // =================== scan prologue (all blocks) ===================
    if (t < BB) { s_src[t] = head[t]; s_src[BB + t] = tail[t]; }
    for (int i = t; i < 2 * MW; i += BLOCK) ((unsigned*)s_scr)[i] = 0u;
    if (t < 16) s_cnt[t] = 0;
    __syncthreads();
    if (t < BB) {
        int h = s_src[t], q = s_src[BB + t];
        atomicOr(&mH[h >> 5], 1u << (h & 31));
        atomicOr(&mT[q >> 5], 1u << (q & 31));
    }
    __syncthreads();

    // =================== scan own stripe ===================
    {
        const int e0 = bid * EPB;
        const int4* eh4 = (const int4*)(eh + e0);
        const int4* et4 = (const int4*)(et + e0);
        for (int p = t; p < EPB / 4; p += BLOCK) {
            int4 h4 = eh4[p];
            int4 t4 = et4[p];
            int hv[4] = {h4.x, h4.y, h4.z, h4.w};
            int tv[4] = {t4.x, t4.y, t4.z, t4.w};
#pragma unroll
            for (int c = 0; c < 4; c++) {
                unsigned e = (unsigned)(e0 + 4 * p + c);
                if ((mH[hv[c] >> 5] >> (hv[c] & 31)) & 1u) {
                    int pos = atomicAdd(&s_cnt[0], 1);
                    __hip_atomic_store(&elistS[(size_t)bid * EPB + pos],
                                       e | TAGE, __ATOMIC_RELAXED,
                                       __HIP_MEMORY_SCOPE_AGENT);
                }
                if ((mT[hv[c] >> 5] >> (hv[c] & 31)) & 1u) {
                    int pos = atomicAdd(&s_cnt[1], 1);
                    __hip_atomic_store(&elistS[(size_t)NE + bid * EPB + pos],
                                       e | TAGE, __ATOMIC_RELAXED,
                                       __HIP_MEMORY_SCOPE_AGENT);
                }
                if ((mT[tv[c] >> 5] >> (tv[c] & 31)) & 1u) {
                    int pos = atomicAdd(&s_cnt[2], 1);
                    __hip_atomic_store(&elistS[(size_t)2 * NE + bid * EPB + pos],
                                       e | TAGE, __ATOMIC_RELAXED,
                                       __HIP_MEMORY_SCOPE_AGENT);
                }
                if ((mH[tv[c] >> 5] >> (tv[c] & 31)) & 1u) {
                    int pos = atomicAdd(&s_cnt[3], 1);
                    __hip_atomic_store(&elistS[(size_t)3 * NE + bid * EPB + pos],
                                       e | TAGE, __ATOMIC_RELAXED,
                                       __HIP_MEMORY_SCOPE_AGENT);
                }
            }
        }
    }
    __syncthreads(); // drains vmcnt: entry stores complete before counts
    if (t < 4)
        __hip_atomic_store(&flags[4 * bid + t], TAGC | (unsigned)s_cnt[t],
                           __ATOMIC_RELAXED, __HIP_MEMORY_SCOPE_AGENT);
    if (bid >= 2) return;

    // =================== tail (block d handles direction d) ===================
    const int d = bid;
    float* hB = hidB + (size_t)d * N_ENTC * ROW;
    float* qacc = qaccB + (size_t)d * BB * ROW;
    int* Ml = MlistB + (size_t)d * NE;

    // weights + embeddings (overlaps other blocks' scans)
    for (int i = t; i < 2 * NDIM * NDIM; i += BLOCK) s_W[i] = Wlin[i];
    if (t < 2 * NDIM) s_b[t] = blin[t];
    {
        int b = t >> 5, k = t & 31;
        s_ht[b * 64 + k] = ent_emb[(size_t)s_src[b] * NDIM + k];
        s_ht[b * 64 + 32 + k] = ent_emb[(size_t)s_src[BB + b] * NDIM + k];
    }
    for (int i = t; i < BB * ROW; i += BLOCK) qacc[i] = 0.f;
    __syncthreads();
    // relation-attention weights, both layers
    for (int l = 0; l < 2; l++) {
        for (int i = t; i < BB * 5; i += BLOCK) {
            int b = i / 5, j = i % 5;
            float s = brel[l * 5 + j];
            for (int k = 0; k < 64; k++)
                s += s_ht[b * 64 + k] * Wrel[l * 320 + k * 5 + j];
            s_h5[i] = fmaxf(s, 0.f);
        }
        __syncthreads();
        for (int i = t; i < BB * ALL_RELC; i += BLOCK) {
            int b = i / ALL_RELC, r = i % ALL_RELC;
            float s = batt[l * ALL_RELC + r];
            for (int j = 0; j < 5; j++)
                s += s_h5[b * 5 + j] * Watt[l * 5 * ALL_RELC + j * ALL_RELC + r];
            s_relw[l * BB * ALL_RELC + i] = 1.0f / (1.0f + expf(-s));
        }
        __syncthreads();
    }

    // poll this direction's 240 count words -> s_cnts[2i]=L1_i, [2i+1]=L2_i
    for (int w = t; w < 2 * NSCAN; w += BLOCK) {
        int i = w >> 1, l = d + (w & 1) * 2;
        unsigned v = __hip_atomic_load(&flags[4 * i + l], __ATOMIC_RELAXED,
                                       __HIP_MEMORY_SCOPE_AGENT);
        while ((v >> 24) != 0x5Au) {
            __builtin_amdgcn_s_sleep(2);
            v = __hip_atomic_load(&flags[4 * i + l], __ATOMIC_RELAXED,
                                  __HIP_MEMORY_SCOPE_AGENT);
        }
        s_cnts[w] = (int)(v & 0xFFFFFFu);
    }
    __syncthreads();

    // compact both lists (LDS if total <= CAPE, else global)
    int ec[2];
    int* clp[2];
    for (int li = 0; li < 2; li++) {
        for (int i = t; i < 128; i += BLOCK)
            s_pf[i] = (i < NSCAN) ? s_cnts[2 * i + li] : 0;
        __syncthreads();
        for (int st = 1; st < 128; st <<= 1) {
            int v = (t < 128 && t >= st) ? s_pf[t - st] : 0;
            __syncthreads();
            if (t < 128) s_pf[t] += v;
            __syncthreads();
        }
        int total = s_pf[NSCAN - 1];
        int* dst = (total <= CAPE) ? (li ? s_cl2 : s_cl1)
                                   : (gcomp + (size_t)(2 * d + li) * NE);
        const unsigned* gl = elistS + (size_t)(d + li * 2) * NE;
        for (int i = wid8; i < NSCAN; i += 8) {
            int c = s_cnts[2 * i + li];
            int off = s_pf[i] - c;
            for (int k = lane; k < c; k += 64) {
                unsigned v = __hip_atomic_load(&gl[(size_t)i * EPB + k],
                                               __ATOMIC_RELAXED,
                                               __HIP_MEMORY_SCOPE_AGENT);
                while (!(v & TAGE)) {
                    __builtin_amdgcn_s_sleep(1);
                    v = __hip_atomic_load(&gl[(size_t)i * EPB + k],
                                          __ATOMIC_RELAXED,
                                          __HIP_MEMORY_SCOPE_AGENT);
                }
                dst[off + k] = (int)(v & (TAGE - 1u));
            }
        }
        ec[li] = total;
        clp[li] = dst;
        __syncthreads();
    }
    const int ec1 = ec[0], ec2 = ec[1];
    const int* cl1p = clp[0];
    const int* cl2p = clp[1];

    // M = distinct heads of compacted L2 (bitmask reuses scan-mask region)
    for (int i = t; i < MW; i += BLOCK) mM[i] = 0u;
    if (t == 0) s_cnt[8] = 0;
    __syncthreads();
    for (int j = t; j < ec2; j += BLOCK) {
        int h = eh[cl2p[j]];
        unsigned bit = 1u << (h & 31);
        unsigned old = atomicOr(&mM[h >> 5], bit);
        if (!(old & bit)) { int p = atomicAdd(&s_cnt[8], 1); Ml[p] = h; }
    }
    __syncthreads();
    const int cm = s_cnt[8];

    // zero hidB rows of M
    {
        float4 z = make_float4(0.f, 0.f, 0.f, 0.f);
        for (int j = wid8; j < cm; j += 8) {
            float4* p = (float4*)(hB + (size_t)Ml[j] * ROW);
            p[lane] = z;
            p[lane + 64] = z;
        }
    }
    __syncthreads();

    // layer-1 messages: sources from LDS (hid0 = ent_emb at init ids)
    {
        const float4* rv = (const float4*)rel_embs;
        for (int j = wid8; j < ec1; j += 8) {
            int e = cl1p[j];
            int tt = et[e];
            if (!((mM[tt >> 5] >> (tt & 31)) & 1u)) continue;
            int r = er[e];
            float wgt = ew[e];
            int h = eh[e];
            float* drow = hB + (size_t)tt * ROW;
#pragma unroll
            for (int ii = 0; ii < 2; ii++) {
                int i4 = lane + 64 * ii;
                int b = i4 >> 3, kq = i4 & 7;
                if (s_src[d * BB + b] != h) continue;
                float c = s_relw[b * ALL_RELC + r] * wgt;
                float4 sv4 = *(const float4*)&s_ht[b * 64 + d * 32 + kq * 4];
                float4 rr = rv[r * 8 + kq];
                atomicAdd(drow + i4 * 4 + 0, sv4.x * c * rr.x);
                atomicAdd(drow + i4 * 4 + 1, sv4.y * c * rr.y);
                atomicAdd(drow + i4 * 4 + 2, sv4.z * c * rr.z);
                atomicAdd(drow + i4 * 4 + 3, sv4.w * c * rr.w);
            }
        }
    }
    __syncthreads();

    // layer-1 linear in-place on M rows
    {
        int b = lane >> 2;
        int j0 = (lane & 3) * 8;
        for (int j = wid8; j < cm; j += 8) {
            float* rowp = hB + (size_t)Ml[j] * ROW + b * NDIM;
            const float4* src = (const float4*)rowp;
            float h[NDIM];
#pragma unroll
            for (int q = 0; q < 8; q++) {
                float4 v = src[q];
                h[q * 4 + 0] = v.x; h[q * 4 + 1] = v.y;
                h[q * 4 + 2] = v.z; h[q * 4 + 3] = v.w;
            }
            float acc[8];
#pragma unroll
            for (int jj = 0; jj < 8; jj++) acc[jj] = s_b[j0 + jj];
#pragma unroll
            for (int k = 0; k < NDIM; k++) {
                float4 w0 = *(const float4*)&s_W[k * NDIM + j0];
                float4 w1 = *(const float4*)&s_W[k * NDIM + j0 + 4];
                float hk = h[k];
                acc[0] += hk * w0.x; acc[1] += hk * w0.y;
                acc[2] += hk * w0.z; acc[3] += hk * w0.w;
                acc[4] += hk * w1.x; acc[5] += hk * w1.y;
                acc[6] += hk * w1.z; acc[7] += hk * w1.w;
            }
            float4 o0, o1;
            o0.x = fmaxf(acc[0], 0.f); o0.y = fmaxf(acc[1], 0.f);
            o0.z = fmaxf(acc[2], 0.f); o0.w = fmaxf(acc[3], 0.f);
            o1.x = fmaxf(acc[4], 0.f); o1.y = fmaxf(acc[5], 0.f);
            o1.z = fmaxf(acc[6], 0.f); o1.w = fmaxf(acc[7], 0.f);
            *(float4*)(rowp + j0) = o0;
            *(float4*)(rowp + j0 + 4) = o1;
        }
    }
    __syncthreads();

    // layer-2 messages: hidB[M] -> Qacc (16 canonical query rows)
    {
        const float* rw2 = s_relw + BB * ALL_RELC;
        const float4* rv2 = (const float4*)(rel_embs + (size_t)ALL_RELC * NDIM);
        for (int j = wid8; j < ec2; j += 8) {
            int e = cl2p[j];
            int r = er[e];
            float wgt = ew[e];
            int q = et[e];
            int slot = 0;
            for (int bb = 0; bb < BB; bb++)
                if (s_src[(1 - d) * BB + bb] == q) { slot = bb; break; }
            const float4* srow = (const float4*)(hB + (size_t)eh[e] * ROW);
            float* drow = qacc + slot * ROW;
#pragma unroll
            for (int ii = 0; ii < 2; ii++) {
                int i4 = lane + 64 * ii;
                int b = i4 >> 3, kq = i4 & 7;
                float c = rw2[b * ALL_RELC + r] * wgt;
                float4 s = srow[i4];
                float4 rr = rv2[r * 8 + kq];
                atomicAdd(drow + i4 * 4 + 0, s.x * c * rr.x);
                atomicAdd(drow + i4 * 4 + 1, s.y * c * rr.y);
                atomicAdd(drow + i4 * 4 + 2, s.z * c * rr.z);
                atomicAdd(drow + i4 * 4 + 3, s.w * c * rr.w);
            }
        }
    }
    __syncthreads();

    // layer-2 linear: only (canon(q_b), sample b) segments
    {
        int b = t >> 5, j = t & 31;
        int q = s_src[(1 - d) * BB + b];
        int slot = 0;
        for (int bb = 0; bb < BB; bb++)
            if (s_src[(1 - d) * BB + bb] == q) { slot = bb; break; }
        const float* hrow = qacc + slot * ROW + b * NDIM;
        float s = s_b[NDIM + j];
        for (int k = 0; k < NDIM; k++)
            s += hrow[k] * s_W[NDIM * NDIM + k * NDIM + j];
        float val = fmaxf(s, 0.f);
        if (d == 1) staging[512 + t] = val;
        else s_relw[t] = val; // block 0 stashes tail_hid in LDS (relw dead)
    }
    __syncthreads();

    // cross-block handoff (R4-proven pattern) + final GEMM on block 0
    if (d == 1) {
        if (t == 0) {
            __builtin_amdgcn_fence(__ATOMIC_RELEASE, "agent");
            __hip_atomic_store(hflag, MAGIC, __ATOMIC_RELAXED,
                               __HIP_MEMORY_SCOPE_AGENT);
        }
        return;
    }
    if (t == 0) {
        while (__hip_atomic_load(hflag, __ATOMIC_RELAXED,
                                 __HIP_MEMORY_SCOPE_AGENT) != MAGIC)
            __builtin_amdgcn_s_sleep(8);
        __builtin_amdgcn_fence(__ATOMIC_ACQUIRE, "agent");
    }
    __syncthreads();

    float* sx = s_relw + 1024; // [16][128] = hemb|temb|head_hid|tail_hid
    {
        int b = t >> 5, k = t & 31;
        sx[b * 128 + k] = s_ht[b * 64 + k];
        sx[b * 128 + 32 + k] = s_ht[b * 64 + 32 + k];
        sx[b * 128 + 64 + k] = staging[512 + b * 32 + k]; // head_hid (dir 1)
        sx[b * 128 + 96 + k] = s_relw[b * 32 + k];        // tail_hid (dir 0)
    }
    __syncthreads();
    for (int o = t; o < BB * EVAL_RELC; o += BLOCK) {
        int b = o / EVAL_RELC, r = o % EVAL_RELC;
        float s = br[r];
        for (int k = 0; k < 128; k++)
            s += sx[b * 128 + k] * Wr[k * EVAL_RELC + r];
        out[o] = s;
    }
}

extern "C" void kernel_launch(void* const* d_in, const int* in_sizes, int n_in,
                              void* d_out, int out_size, void* d_ws,
                              size_t ws_size, hipStream_t stream)
{
    const int* head = (const int*)d_in[0];
    const int* tail = (const int*)d_in[1];
    const int* eh = (const int*)d_in[2];
    const int* et = (const int*)d_in[3];
    const int* er = (const int*)d_in[4];
    const float* ew = (const float*)d_in[5];
    const float* ent_emb = (const float*)d_in[6];
    const float* rel_embs = (const float*)d_in[7];
    const float* Wlin = (const float*)d_in[8];
    const float* blin = (const float*)d_in[9];
    const float* Wrel = (const float*)d_in[10];
    const float* brel = (const float*)d_in[11];
    const float* Watt = (const float*)d_in[12];
    const float* batt = (const float*)d_in[13];
    const float* Wr = (const float*)d_in[14];
    const float* br = (const float*)d_in[15];
    float* out = (float*)d_out;
    float* ws = (float*)d_ws;

    emer_scan_path<<<NSCAN, BLOCK, 0, stream>>>(
        head, tail, eh, et, er, ew, ent_emb, rel_embs, Wlin, blin,
        Wrel, brel, Watt, batt, Wr, br, out, ws);
}